// Round 3
// baseline (92.235 us; speedup 1.0000x reference)
//
#include <hip/hip_runtime.h>

// LiftSplatShoot: out(B,N,3+C,H,W,D) = concat(world, feats_broadcast)
// B=4 N=6 C=80 H=16 W=44 D=59 -> 82,739,712 fp32 (~331 MB). Write-bound.
// Single kernel: world blocks (ch<3) recompute softmax+M locally (trivial),
// feature blocks are pure replication. Per-thread (w,d) index tables hoisted
// out of the row loop.

#define BB 4
#define NN 6
#define CC 80
#define HH 16
#define WW 44
#define DD 59
#define BN (BB*NN)        // 24
#define PP (HH*WW)        // 704
#define CHO (CC+3)        // 83
#define WD (WW*DD)        // 2596
#define NQ4 (WD/4)        // 649
#define HSPLIT 2
#define HLOC (HH/HSPLIT)  // 8
#define DSTEP (0.9f/58.f)

typedef float fx4 __attribute__((ext_vector_type(4)));

__device__ inline float waveMax(float v) {
#pragma unroll
    for (int o = 32; o; o >>= 1) v = fmaxf(v, __shfl_xor(v, o));
    return v;
}
__device__ inline float waveSum(float v) {
#pragma unroll
    for (int o = 32; o; o >>= 1) v += __shfl_xor(v, o);
    return v;
}

__global__ __launch_bounds__(256) void lss_all(const float* __restrict__ feats,
                                               const float* __restrict__ intr,
                                               const float* __restrict__ extr,
                                               float* __restrict__ out) {
    const int blk  = blockIdx.x;
    const int hs   = blk & (HSPLIT - 1);
    const int chbn = blk >> 1;            // HSPLIT == 2
    const int ch   = chbn % CHO;
    const int bn   = chbn / CHO;
    const int tid  = threadIdx.x;
    const bool world = (ch < 3);

    __shared__ float sf[PP];              // staged softmax channel (world only)
    __shared__ float valw[HLOC][WW + 1];  // per-row w-values (+1 pad for w+1 read)
    __shared__ float sred[4];
    __shared__ float sbc[2];

    float tval = 0.f;

    if (world) {
        // --- softmax of channel C-1 over all 704 spatial positions ---
        const float* f = feats + ((size_t)bn * CC + (CC - 1)) * PP;
        float m = -1e30f;
        for (int p = tid; p < PP; p += 256) { float v = f[p]; sf[p] = v; m = fmaxf(m, v); }
        m = waveMax(m);
        if ((tid & 63) == 0) sred[tid >> 6] = m;
        __syncthreads();
        if (tid == 0) sbc[0] = fmaxf(fmaxf(sred[0], sred[1]), fmaxf(sred[2], sred[3]));
        __syncthreads();
        const float mm = sbc[0];
        float s = 0.f;
        for (int p = tid; p < PP; p += 256) { float e = expf(sf[p] - mm); sf[p] = e; s += e; }
        s = waveSum(s);
        if ((tid & 63) == 0) sred[tid >> 6] = s;
        __syncthreads();
        if (tid == 0) sbc[1] = sred[0] + sred[1] + sred[2] + sred[3];
        __syncthreads();
        const float inv = 1.0f / sbc[1];

        // --- row ch of M = R * K^-1 (uniform across threads, once per block) ---
        const float* K = intr + bn * 16;
        float a = K[0], b = K[1], c = K[2];
        float d = K[4], e = K[5], ff = K[6];
        float g = K[8], h9 = K[9], i9 = K[10];
        float det = a * (e * i9 - ff * h9) - b * (d * i9 - ff * g) + c * (d * h9 - e * g);
        float id = 1.0f / det;
        float kinv[9] = {
            (e * i9 - ff * h9) * id, (c * h9 - b * i9) * id, (b * ff - c * e) * id,
            (ff * g - d * i9) * id,  (a * i9 - c * g) * id,  (c * d - a * ff) * id,
            (d * h9 - e * g) * id,   (b * g - a * h9) * id,  (a * e - b * d) * id
        };
        const float* E = extr + bn * 16;
        float M0 = E[ch * 4 + 0] * kinv[0] + E[ch * 4 + 1] * kinv[3] + E[ch * 4 + 2] * kinv[6];
        float M1 = E[ch * 4 + 0] * kinv[1] + E[ch * 4 + 1] * kinv[4] + E[ch * 4 + 2] * kinv[7];
        float M2 = E[ch * 4 + 0] * kinv[2] + E[ch * 4 + 1] * kinv[5] + E[ch * 4 + 2] * kinv[8];
        tval = E[ch * 4 + 3];

        for (int t2 = tid; t2 < HLOC * WW; t2 += 256) {
            int hl = t2 / WW;
            int w  = t2 - hl * WW;
            int h  = hs * HLOC + hl;
            float ray = M0 * (float)w + M1 * (float)h + M2;
            valw[hl][w] = ray * sf[h * WW + w] * inv;
        }
    } else {
        const float* frow = feats + ((size_t)bn * CC + (ch - 3)) * PP + hs * HLOC * WW;
        for (int t2 = tid; t2 < HLOC * WW; t2 += 256) {
            int hl = t2 / WW;
            int w  = t2 - hl * WW;
            valw[hl][w] = frow[t2];
        }
    }
    if (tid < HLOC) valw[tid][WW] = 0.f;   // pad (read but never selected)
    __syncthreads();

    // --- per-thread index tables: pure function of tid, reused for all rows ---
    int   wA[3];
    int   cross[3][4];
    float sc[3][4];
#pragma unroll
    for (int i = 0; i < 3; ++i) {
        int q = tid + 256 * i;
        if (q < NQ4) {
            int base = 4 * q;
            int w    = base / DD;
            int dlo  = base - DD * w;
            wA[i] = w;
#pragma unroll
            for (int k = 0; k < 4; ++k) {
                int dd   = dlo + k;
                int cr   = (dd >= DD) ? 1 : 0;
                int deff = dd - cr * DD;
                cross[i][k] = cr;
                sc[i][k] = 0.1f + (float)deff * DSTEP;
            }
        }
    }

    float* obase = out + (((size_t)(bn * CHO + ch)) * HH + hs * HLOC) * WD;

    if (world) {
        for (int hl = 0; hl < HLOC; ++hl) {
            const float* vr = valw[hl];
            float* orow = obase + (size_t)hl * WD;
#pragma unroll
            for (int i = 0; i < 3; ++i) {
                int q = tid + 256 * i;
                if (q < NQ4) {
                    float v0 = vr[wA[i]];
                    float v1 = vr[wA[i] + 1];
                    fx4 r;
                    r.x = (cross[i][0] ? v1 : v0) * sc[i][0] + tval;
                    r.y = (cross[i][1] ? v1 : v0) * sc[i][1] + tval;
                    r.z = (cross[i][2] ? v1 : v0) * sc[i][2] + tval;
                    r.w = (cross[i][3] ? v1 : v0) * sc[i][3] + tval;
                    __builtin_nontemporal_store(r, (fx4*)(orow + 4 * q));
                }
            }
        }
    } else {
        for (int hl = 0; hl < HLOC; ++hl) {
            const float* vr = valw[hl];
            float* orow = obase + (size_t)hl * WD;
#pragma unroll
            for (int i = 0; i < 3; ++i) {
                int q = tid + 256 * i;
                if (q < NQ4) {
                    float v0 = vr[wA[i]];
                    float v1 = vr[wA[i] + 1];
                    fx4 r;
                    r.x = cross[i][0] ? v1 : v0;
                    r.y = cross[i][1] ? v1 : v0;
                    r.z = cross[i][2] ? v1 : v0;
                    r.w = cross[i][3] ? v1 : v0;
                    __builtin_nontemporal_store(r, (fx4*)(orow + 4 * q));
                }
            }
        }
    }
}

extern "C" void kernel_launch(void* const* d_in, const int* in_sizes, int n_in,
                              void* d_out, int out_size, void* d_ws, size_t ws_size,
                              hipStream_t stream) {
    const float* feats = (const float*)d_in[0];
    const float* intr  = (const float*)d_in[1];
    const float* extr  = (const float*)d_in[2];
    float* out = (float*)d_out;

    lss_all<<<BN * CHO * HSPLIT, 256, 0, stream>>>(feats, intr, extr, out);
}

// Round 4
// 72.009 us; speedup vs baseline: 1.2809x; 1.2809x over previous
//
#include <hip/hip_runtime.h>

// LiftSplatShoot: out(B,N,3+C,H,W,D) = concat(world, feats_broadcast)
// B=4 N=6 C=80 H=16 W=44 D=59 -> 82,739,712 fp32 (~331 MB). Write-bound.
// Single kernel, regular (cached) float4 stores — NT stores regressed 17%
// (bypassed the 256MB L3 that absorbs the write burst).

#define BB 4
#define NN 6
#define CC 80
#define HH 16
#define WW 44
#define DD 59
#define BN (BB*NN)        // 24
#define PP (HH*WW)        // 704
#define CHO (CC+3)        // 83
#define WD (WW*DD)        // 2596
#define NQ4 (WD/4)        // 649
#define HSPLIT 2
#define HLOC (HH/HSPLIT)  // 8
#define DSTEP (0.9f/58.f)

typedef float fx4 __attribute__((ext_vector_type(4)));

__device__ inline float waveMax(float v) {
#pragma unroll
    for (int o = 32; o; o >>= 1) v = fmaxf(v, __shfl_xor(v, o));
    return v;
}
__device__ inline float waveSum(float v) {
#pragma unroll
    for (int o = 32; o; o >>= 1) v += __shfl_xor(v, o);
    return v;
}

__global__ __launch_bounds__(256) void lss_all(const float* __restrict__ feats,
                                               const float* __restrict__ intr,
                                               const float* __restrict__ extr,
                                               float* __restrict__ out) {
    const int blk  = blockIdx.x;
    const int hs   = blk & (HSPLIT - 1);
    const int chbn = blk >> 1;            // HSPLIT == 2
    const int ch   = chbn % CHO;
    const int bn   = chbn / CHO;
    const int tid  = threadIdx.x;
    const bool world = (ch < 3);

    __shared__ float sf[PP];              // staged softmax channel (world only)
    __shared__ float valw[HLOC][WW + 1];  // per-row w-values (+1 pad for w+1 read)
    __shared__ float sred[4];
    __shared__ float sbc[2];

    float tval = 0.f;

    if (world) {
        // --- softmax of channel C-1 over all 704 spatial positions ---
        const float* f = feats + ((size_t)bn * CC + (CC - 1)) * PP;
        float m = -1e30f;
        for (int p = tid; p < PP; p += 256) { float v = f[p]; sf[p] = v; m = fmaxf(m, v); }
        m = waveMax(m);
        if ((tid & 63) == 0) sred[tid >> 6] = m;
        __syncthreads();
        if (tid == 0) sbc[0] = fmaxf(fmaxf(sred[0], sred[1]), fmaxf(sred[2], sred[3]));
        __syncthreads();
        const float mm = sbc[0];
        float s = 0.f;
        for (int p = tid; p < PP; p += 256) { float e = expf(sf[p] - mm); sf[p] = e; s += e; }
        s = waveSum(s);
        if ((tid & 63) == 0) sred[tid >> 6] = s;
        __syncthreads();
        if (tid == 0) sbc[1] = sred[0] + sred[1] + sred[2] + sred[3];
        __syncthreads();
        const float inv = 1.0f / sbc[1];

        // --- row ch of M = R * K^-1 (uniform across threads, once per block) ---
        const float* K = intr + bn * 16;
        float a = K[0], b = K[1], c = K[2];
        float d = K[4], e = K[5], ff = K[6];
        float g = K[8], h9 = K[9], i9 = K[10];
        float det = a * (e * i9 - ff * h9) - b * (d * i9 - ff * g) + c * (d * h9 - e * g);
        float id = 1.0f / det;
        float kinv[9] = {
            (e * i9 - ff * h9) * id, (c * h9 - b * i9) * id, (b * ff - c * e) * id,
            (ff * g - d * i9) * id,  (a * i9 - c * g) * id,  (c * d - a * ff) * id,
            (d * h9 - e * g) * id,   (b * g - a * h9) * id,  (a * e - b * d) * id
        };
        const float* E = extr + bn * 16;
        float M0 = E[ch * 4 + 0] * kinv[0] + E[ch * 4 + 1] * kinv[3] + E[ch * 4 + 2] * kinv[6];
        float M1 = E[ch * 4 + 0] * kinv[1] + E[ch * 4 + 1] * kinv[4] + E[ch * 4 + 2] * kinv[7];
        float M2 = E[ch * 4 + 0] * kinv[2] + E[ch * 4 + 1] * kinv[5] + E[ch * 4 + 2] * kinv[8];
        tval = E[ch * 4 + 3];

        for (int t2 = tid; t2 < HLOC * WW; t2 += 256) {
            int hl = t2 / WW;
            int w  = t2 - hl * WW;
            int h  = hs * HLOC + hl;
            float ray = M0 * (float)w + M1 * (float)h + M2;
            valw[hl][w] = ray * sf[h * WW + w] * inv;
        }
    } else {
        const float* frow = feats + ((size_t)bn * CC + (ch - 3)) * PP + hs * HLOC * WW;
        for (int t2 = tid; t2 < HLOC * WW; t2 += 256) {
            int hl = t2 / WW;
            int w  = t2 - hl * WW;
            valw[hl][w] = frow[t2];
        }
    }
    if (tid < HLOC) valw[tid][WW] = 0.f;   // pad (read but never selected)
    __syncthreads();

    // --- per-thread index tables: pure function of tid, reused for all rows ---
    int   wA[3];
    int   cross[3][4];
    float sc[3][4];
#pragma unroll
    for (int i = 0; i < 3; ++i) {
        int q = tid + 256 * i;
        if (q < NQ4) {
            int base = 4 * q;
            int w    = base / DD;
            int dlo  = base - DD * w;
            wA[i] = w;
#pragma unroll
            for (int k = 0; k < 4; ++k) {
                int dd   = dlo + k;
                int cr   = (dd >= DD) ? 1 : 0;
                int deff = dd - cr * DD;
                cross[i][k] = cr;
                sc[i][k] = 0.1f + (float)deff * DSTEP;
            }
        }
    }

    float* obase = out + (((size_t)(bn * CHO + ch)) * HH + hs * HLOC) * WD;

    if (world) {
        for (int hl = 0; hl < HLOC; ++hl) {
            const float* vr = valw[hl];
            float* orow = obase + (size_t)hl * WD;
#pragma unroll
            for (int i = 0; i < 3; ++i) {
                int q = tid + 256 * i;
                if (q < NQ4) {
                    float v0 = vr[wA[i]];
                    float v1 = vr[wA[i] + 1];
                    fx4 r;
                    r.x = (cross[i][0] ? v1 : v0) * sc[i][0] + tval;
                    r.y = (cross[i][1] ? v1 : v0) * sc[i][1] + tval;
                    r.z = (cross[i][2] ? v1 : v0) * sc[i][2] + tval;
                    r.w = (cross[i][3] ? v1 : v0) * sc[i][3] + tval;
                    *(fx4*)(orow + 4 * q) = r;
                }
            }
        }
    } else {
        for (int hl = 0; hl < HLOC; ++hl) {
            const float* vr = valw[hl];
            float* orow = obase + (size_t)hl * WD;
#pragma unroll
            for (int i = 0; i < 3; ++i) {
                int q = tid + 256 * i;
                if (q < NQ4) {
                    float v0 = vr[wA[i]];
                    float v1 = vr[wA[i] + 1];
                    fx4 r;
                    r.x = cross[i][0] ? v1 : v0;
                    r.y = cross[i][1] ? v1 : v0;
                    r.z = cross[i][2] ? v1 : v0;
                    r.w = cross[i][3] ? v1 : v0;
                    *(fx4*)(orow + 4 * q) = r;
                }
            }
        }
    }
}

extern "C" void kernel_launch(void* const* d_in, const int* in_sizes, int n_in,
                              void* d_out, int out_size, void* d_ws, size_t ws_size,
                              hipStream_t stream) {
    const float* feats = (const float*)d_in[0];
    const float* intr  = (const float*)d_in[1];
    const float* extr  = (const float*)d_in[2];
    float* out = (float*)d_out;

    lss_all<<<BN * CHO * HSPLIT, 256, 0, stream>>>(feats, intr, extr, out);
}

// Round 5
// 70.199 us; speedup vs baseline: 1.3139x; 1.0258x over previous
//
#include <hip/hip_runtime.h>

// LiftSplatShoot: out(B,N,3+C,H,W,D) = concat(world, feats_broadcast)
// B=4 N=6 C=80 H=16 W=44 D=59 -> 82,739,712 fp32 (~331 MB). Write-bound.
// Round 5: HSPLIT=1 — 1992 blocks, each writes a full (bn,ch) slab of
// 16 rows (166 KB contiguous); per-thread (w,d) tables reused over 16 rows.
// Regular cached float4 stores (NT regressed 17% in round 3).

#define BB 4
#define NN 6
#define CC 80
#define HH 16
#define WW 44
#define DD 59
#define BN (BB*NN)        // 24
#define PP (HH*WW)        // 704
#define CHO (CC+3)        // 83
#define WD (WW*DD)        // 2596
#define NQ4 (WD/4)        // 649
#define HLOC HH           // 16 rows per block
#define DSTEP (0.9f/58.f)

typedef float fx4 __attribute__((ext_vector_type(4)));

__device__ inline float waveMax(float v) {
#pragma unroll
    for (int o = 32; o; o >>= 1) v = fmaxf(v, __shfl_xor(v, o));
    return v;
}
__device__ inline float waveSum(float v) {
#pragma unroll
    for (int o = 32; o; o >>= 1) v += __shfl_xor(v, o);
    return v;
}

__global__ __launch_bounds__(256) void lss_all(const float* __restrict__ feats,
                                               const float* __restrict__ intr,
                                               const float* __restrict__ extr,
                                               float* __restrict__ out) {
    const int blk  = blockIdx.x;
    const int ch   = blk % CHO;
    const int bn   = blk / CHO;
    const int tid  = threadIdx.x;
    const bool world = (ch < 3);

    __shared__ float sf[PP];              // staged softmax channel (world only)
    __shared__ float valw[HLOC][WW + 1];  // per-row w-values (+1 pad for w+1 read)
    __shared__ float sred[4];
    __shared__ float sbc[2];

    float tval = 0.f;

    if (world) {
        // --- softmax of channel C-1 over all 704 spatial positions ---
        const float* f = feats + ((size_t)bn * CC + (CC - 1)) * PP;
        float m = -1e30f;
        for (int p = tid; p < PP; p += 256) { float v = f[p]; sf[p] = v; m = fmaxf(m, v); }
        m = waveMax(m);
        if ((tid & 63) == 0) sred[tid >> 6] = m;
        __syncthreads();
        if (tid == 0) sbc[0] = fmaxf(fmaxf(sred[0], sred[1]), fmaxf(sred[2], sred[3]));
        __syncthreads();
        const float mm = sbc[0];
        float s = 0.f;
        for (int p = tid; p < PP; p += 256) { float e = expf(sf[p] - mm); sf[p] = e; s += e; }
        s = waveSum(s);
        if ((tid & 63) == 0) sred[tid >> 6] = s;
        __syncthreads();
        if (tid == 0) sbc[1] = sred[0] + sred[1] + sred[2] + sred[3];
        __syncthreads();
        const float inv = 1.0f / sbc[1];

        // --- row ch of M = R * K^-1 (uniform across threads, once per block) ---
        const float* K = intr + bn * 16;
        float a = K[0], b = K[1], c = K[2];
        float d = K[4], e = K[5], ff = K[6];
        float g = K[8], h9 = K[9], i9 = K[10];
        float det = a * (e * i9 - ff * h9) - b * (d * i9 - ff * g) + c * (d * h9 - e * g);
        float id = 1.0f / det;
        float kinv[9] = {
            (e * i9 - ff * h9) * id, (c * h9 - b * i9) * id, (b * ff - c * e) * id,
            (ff * g - d * i9) * id,  (a * i9 - c * g) * id,  (c * d - a * ff) * id,
            (d * h9 - e * g) * id,   (b * g - a * h9) * id,  (a * e - b * d) * id
        };
        const float* E = extr + bn * 16;
        float M0 = E[ch * 4 + 0] * kinv[0] + E[ch * 4 + 1] * kinv[3] + E[ch * 4 + 2] * kinv[6];
        float M1 = E[ch * 4 + 0] * kinv[1] + E[ch * 4 + 1] * kinv[4] + E[ch * 4 + 2] * kinv[7];
        float M2 = E[ch * 4 + 0] * kinv[2] + E[ch * 4 + 1] * kinv[5] + E[ch * 4 + 2] * kinv[8];
        tval = E[ch * 4 + 3];

        // h*WW + w == t2 when the block owns all 16 rows
        for (int t2 = tid; t2 < PP; t2 += 256) {
            int hl = t2 / WW;
            int w  = t2 - hl * WW;
            float ray = M0 * (float)w + M1 * (float)hl + M2;
            valw[hl][w] = ray * sf[t2] * inv;
        }
    } else {
        const float* frow = feats + ((size_t)bn * CC + (ch - 3)) * PP;
        for (int t2 = tid; t2 < PP; t2 += 256) {
            int hl = t2 / WW;
            int w  = t2 - hl * WW;
            valw[hl][w] = frow[t2];
        }
    }
    if (tid < HLOC) valw[tid][WW] = 0.f;   // pad (read but never selected)
    __syncthreads();

    // --- per-thread index tables: pure function of tid, reused for all 16 rows ---
    int   wA[3];
    int   cross[3][4];
    float sc[3][4];
#pragma unroll
    for (int i = 0; i < 3; ++i) {
        int q = tid + 256 * i;
        if (q < NQ4) {
            int base = 4 * q;
            int w    = base / DD;
            int dlo  = base - DD * w;
            wA[i] = w;
#pragma unroll
            for (int k = 0; k < 4; ++k) {
                int dd   = dlo + k;
                int cr   = (dd >= DD) ? 1 : 0;
                int deff = dd - cr * DD;
                cross[i][k] = cr;
                sc[i][k] = 0.1f + (float)deff * DSTEP;
            }
        }
    }

    float* obase = out + ((size_t)(bn * CHO + ch)) * HH * WD;

    if (world) {
        for (int hl = 0; hl < HLOC; ++hl) {
            const float* vr = valw[hl];
            float* orow = obase + (size_t)hl * WD;
#pragma unroll
            for (int i = 0; i < 3; ++i) {
                int q = tid + 256 * i;
                if (q < NQ4) {
                    float v0 = vr[wA[i]];
                    float v1 = vr[wA[i] + 1];
                    fx4 r;
                    r.x = (cross[i][0] ? v1 : v0) * sc[i][0] + tval;
                    r.y = (cross[i][1] ? v1 : v0) * sc[i][1] + tval;
                    r.z = (cross[i][2] ? v1 : v0) * sc[i][2] + tval;
                    r.w = (cross[i][3] ? v1 : v0) * sc[i][3] + tval;
                    *(fx4*)(orow + 4 * q) = r;
                }
            }
        }
    } else {
        for (int hl = 0; hl < HLOC; ++hl) {
            const float* vr = valw[hl];
            float* orow = obase + (size_t)hl * WD;
#pragma unroll
            for (int i = 0; i < 3; ++i) {
                int q = tid + 256 * i;
                if (q < NQ4) {
                    float v0 = vr[wA[i]];
                    float v1 = vr[wA[i] + 1];
                    fx4 r;
                    r.x = cross[i][0] ? v1 : v0;
                    r.y = cross[i][1] ? v1 : v0;
                    r.z = cross[i][2] ? v1 : v0;
                    r.w = cross[i][3] ? v1 : v0;
                    *(fx4*)(orow + 4 * q) = r;
                }
            }
        }
    }
}

extern "C" void kernel_launch(void* const* d_in, const int* in_sizes, int n_in,
                              void* d_out, int out_size, void* d_ws, size_t ws_size,
                              hipStream_t stream) {
    const float* feats = (const float*)d_in[0];
    const float* intr  = (const float*)d_in[1];
    const float* extr  = (const float*)d_in[2];
    float* out = (float*)d_out;

    lss_all<<<BN * CHO, 256, 0, stream>>>(feats, intr, extr, out);
}